// Round 11
// baseline (142.500 us; speedup 1.0000x reference)
//
#include <hip/hip_runtime.h>

#define B     128
#define NE    14951
#define NEP   14976     // 117*128, padded entity count
#define NR    1345
#define D     200
#define NL    116
#define D2    100
#define EB    4         // batches per WAVE-GROUP (per thread); block covers 2 quads
#define LOG2E 1.4426950408889634f

// ---- ws layout (floats), fast path ----
#define OFF_ET4  0                          // [50][NEP][4]  E transposed, d-chunked
#define OFF_LT4  (OFF_ET4 + 50*NEP*4)       // [29][NEP][4]  lit transposed
#define OFF_ST4  (OFF_LT4 + 29*NEP*4)       // [29][NEP][4]  q*L^2 transposed
#define OFF_WB   (OFF_ST4 + 29*NEP*4)       // [128][200]    complex weight w[b][d]
#define OFF_UB   (OFF_WB + 128*200)         // [128][116]    u = -2*q*a
#define OFF_FB   (OFF_UB + 128*116)         // [128][116]    w' = wnf*exp2(q*a^2)
#define WS_FLOATS (OFF_FB + 128*116)
#define WS_NEEDED ((size_t)WS_FLOATS * 4)

// ---------------- fused prep: 3 roles by blockIdx range ----------------
#define NB_A 3042
#define NB_B 1872
#define NB_C 64

__global__ __launch_bounds__(256) void prep_all(
    const int* __restrict__ e1_idx, const int* __restrict__ r_idx,
    const float* __restrict__ E, const float* __restrict__ R,
    const float* __restrict__ nf, const float* __restrict__ lit,
    const float* __restrict__ c, const float* __restrict__ var,
    float* __restrict__ ws)
{
    const int bid = blockIdx.x;
    const int t   = threadIdx.x;

    if (bid < NB_A) {                       // ---- transpose E ----
        const int ebk = bid % 234;
        const int cq  = (bid / 234) * 4 + (t >> 6);
        const int e   = ebk * 64 + (t & 63);
        if (cq >= 50) return;
        float4 v = make_float4(0.f, 0.f, 0.f, 0.f);
        if (e < NE) v = *(const float4*)(E + e*D + 4*cq);
        ((float4*)(ws + OFF_ET4))[cq*NEP + e] = v;
    } else if (bid < NB_A + NB_B) {         // ---- transpose lit + q*L^2 ----
        const int idx = bid - NB_A;
        const int ebk = idx % 234;
        const int cq  = (idx / 234) * 4 + (t >> 6);
        const int e   = ebk * 64 + (t & 63);
        if (cq >= 29) return;
        float4 L = make_float4(0.f, 0.f, 0.f, 0.f);
        if (e < NE) L = *(const float4*)(lit + e*NL + 4*cq);
        float4 vv = *(const float4*)(var + 4*cq);
        float4 s;
        s.x = (-LOG2E / vv.x) * L.x * L.x;
        s.y = (-LOG2E / vv.y) * L.y * L.y;
        s.z = (-LOG2E / vv.z) * L.z * L.z;
        s.w = (-LOG2E / vv.w) * L.w * L.w;
        ((float4*)(ws + OFF_LT4))[cq*NEP + e] = L;
        ((float4*)(ws + OFF_ST4))[cq*NEP + e] = s;
    } else {                                // ---- per-batch prep ----
        const int b  = (bid - NB_A - NB_B) * 2 + (t >> 7);
        const int tt = t & 127;
        const int e1 = e1_idx[b];
        const int r  = r_idx[b];
        float* wb = ws + OFF_WB;
        float* ub = ws + OFF_UB;
        float* fb = ws + OFF_FB;
        if (tt < D2) {
            float e1r = E[e1*D + tt],      e1i = E[e1*D + D2 + tt];
            float rr  = R[r*D + tt],       ri  = R[r*D + D2 + tt];
            wb[b*D + tt]      = e1r*rr - e1i*ri;
            wb[b*D + D2 + tt] = e1r*ri + e1i*rr;
        }
        if (tt < NL) {
            float a = lit[e1*NL + tt] - c[tt];
            float q = -LOG2E / var[tt];
            ub[b*NL + tt] = -2.0f * q * a;
            fb[b*NL + tt] = nf[r*NL + tt] * __builtin_amdgcn_exp2f(q * a * a);
        }
    }
}

// ---------------- main: 256 threads = 2 wave-pairs sharing one e-slice ----------------
// Per-wave code identical to the 51.5us R6 kernel (EB=4, SMEM scalars, 4-deep
// prefetch, NO barriers). The two 128-thread sub-groups issue identical
// per-lane table addresses -> trailing waves hit L1 instead of L2, halving
// L2 table traffic (the measured ~23us stall source).

#define SL_STEP(pf, cq) do {                                              \
    _Pragma("unroll")                                                     \
    for (int j = 0; j < EB; ++j) {                                        \
        float4 wj = *(const float4*)(wb + (b0+j)*D + 4*(cq));             \
        acc[j] = fmaf(wj.x, (pf).x, acc[j]);                              \
        acc[j] = fmaf(wj.y, (pf).y, acc[j]);                              \
        acc[j] = fmaf(wj.z, (pf).z, acc[j]);                              \
        acc[j] = fmaf(wj.w, (pf).w, acc[j]);                              \
    }                                                                     \
} while (0)

#define SN_STEP(lv, sv, cq) do {                                          \
    _Pragma("unroll")                                                     \
    for (int j = 0; j < EB; ++j) {                                        \
        float4 uj = *(const float4*)(ub + (b0+j)*NL + 4*(cq));            \
        float4 fj = *(const float4*)(fb + (b0+j)*NL + 4*(cq));            \
        acc[j] = fmaf(fj.x, __builtin_amdgcn_exp2f(fmaf(uj.x,(lv).x,(sv).x)), acc[j]); \
        acc[j] = fmaf(fj.y, __builtin_amdgcn_exp2f(fmaf(uj.y,(lv).y,(sv).y)), acc[j]); \
        acc[j] = fmaf(fj.z, __builtin_amdgcn_exp2f(fmaf(uj.z,(lv).z,(sv).z)), acc[j]); \
        acc[j] = fmaf(fj.w, __builtin_amdgcn_exp2f(fmaf(uj.w,(lv).w,(sv).w)), acc[j]); \
    }                                                                     \
} while (0)

__global__ __launch_bounds__(256) void score_kernel(
    const float* __restrict__ et4, const float* __restrict__ lt4,
    const float* __restrict__ st4, const float* __restrict__ wb,
    const float* __restrict__ ub,  const float* __restrict__ fb,
    float* __restrict__ out)
{
    // grid = 1872 = 117 eblk * 16 bblk; partition e-range per XCD (lid&7)
    const int lid  = blockIdx.x;
    const int p    = (lid & 7) * 234 + (lid >> 3);
    const int eblk = p >> 4;            // 0..116
    const int bblk = p & 15;            // 0..15
    const int sub  = threadIdx.x >> 7;  // 0..1 (wave-pair index)
    const int e    = eblk * 128 + (threadIdx.x & 127);
    const int b0   = bblk * (2*EB) + sub * EB;

    float acc[EB];
#pragma unroll
    for (int j = 0; j < EB; ++j) acc[j] = 0.f;

    const float4* E4 = (const float4*)et4;
    const float4* L4 = (const float4*)lt4;
    const float4* S4 = (const float4*)st4;

    // ---- score_l: 50 chunks, 4-deep rolling prefetch, named slots ----
    {
        float4 pf0 = E4[0*NEP + e];
        float4 pf1 = E4[1*NEP + e];
        float4 pf2 = E4[2*NEP + e];
        float4 pf3 = E4[3*NEP + e];
        for (int cq0 = 0; cq0 < 48; cq0 += 4) {
            SL_STEP(pf0, cq0 + 0); pf0 = E4[min(cq0 + 4, 49)*NEP + e];
            SL_STEP(pf1, cq0 + 1); pf1 = E4[min(cq0 + 5, 49)*NEP + e];
            SL_STEP(pf2, cq0 + 2); pf2 = E4[min(cq0 + 6, 49)*NEP + e];
            SL_STEP(pf3, cq0 + 3); pf3 = E4[min(cq0 + 7, 49)*NEP + e];
        }
        // after loop: pf0 = chunk 48 (loaded at cq0=44), pf1 = chunk 49
        SL_STEP(pf0, 48);
        SL_STEP(pf1, 49);
    }

    // ---- score_n: 29 chunks, 4-deep rolling prefetch ----
    {
        float4 lv0 = L4[0*NEP + e], sv0 = S4[0*NEP + e];
        float4 lv1 = L4[1*NEP + e], sv1 = S4[1*NEP + e];
        float4 lv2 = L4[2*NEP + e], sv2 = S4[2*NEP + e];
        float4 lv3 = L4[3*NEP + e], sv3 = S4[3*NEP + e];
        for (int cq0 = 0; cq0 < 28; cq0 += 4) {
            SN_STEP(lv0, sv0, cq0 + 0);
            lv0 = L4[min(cq0 + 4, 28)*NEP + e]; sv0 = S4[min(cq0 + 4, 28)*NEP + e];
            SN_STEP(lv1, sv1, cq0 + 1);
            lv1 = L4[min(cq0 + 5, 28)*NEP + e]; sv1 = S4[min(cq0 + 5, 28)*NEP + e];
            SN_STEP(lv2, sv2, cq0 + 2);
            lv2 = L4[min(cq0 + 6, 28)*NEP + e]; sv2 = S4[min(cq0 + 6, 28)*NEP + e];
            SN_STEP(lv3, sv3, cq0 + 3);
            lv3 = L4[min(cq0 + 7, 28)*NEP + e]; sv3 = S4[min(cq0 + 7, 28)*NEP + e];
        }
        // after loop: lv0/sv0 = chunk 28 (loaded at cq0=24)
        SN_STEP(lv0, sv0, 28);
    }

    // ---- sigmoid + coalesced store ----
    if (e < NE) {
#pragma unroll
        for (int j = 0; j < EB; ++j) {
            float s = __builtin_amdgcn_rcpf(1.0f + __builtin_amdgcn_exp2f(acc[j] * -LOG2E));
            out[(b0+j)*NE + e] = s;
        }
    }
}

// ---------------- legacy fallback (ws < 26 MB) ----------------

#define ET  4
#define OFF_W   0
#define OFF_A   25600
#define OFF_WNF 40448
#define OFF_NQ  55296

__global__ __launch_bounds__(128) void prep_kernel_legacy(
    const int* __restrict__ e1_idx, const int* __restrict__ r_idx,
    const float* __restrict__ E, const float* __restrict__ R,
    const float* __restrict__ nf, const float* __restrict__ lit,
    const float* __restrict__ c, const float* __restrict__ var,
    float* __restrict__ ws)
{
    const int b = blockIdx.x;
    const int t = threadIdx.x;
    const int e1 = e1_idx[b];
    const int r  = r_idx[b];
    if (t < D2) {
        float e1r = E[e1*D + t], e1i = E[e1*D + D2 + t];
        float rr  = R[r*D + t],  ri  = R[r*D + D2 + t];
        ws[OFF_W + (t >> 2)*512        + (b << 2) + (t & 3)] = e1r*rr - e1i*ri;
        ws[OFF_W + ((t >> 2) + 25)*512 + (b << 2) + (t & 3)] = e1r*ri + e1i*rr;
    }
    if (t < NL) {
        ws[OFF_A   + (t >> 2)*512 + (b << 2) + (t & 3)] = lit[e1*NL + t] - c[t];
        ws[OFF_WNF + (t >> 2)*512 + (b << 2) + (t & 3)] = nf[r*NL + t];
        if (b == 0) ws[OFF_NQ + t] = -LOG2E / var[t];
    }
}

__global__ __launch_bounds__(128) void main_kernel_legacy(
    const float* __restrict__ E, const float* __restrict__ lit,
    const float* __restrict__ ws, float* __restrict__ out)
{
    const int b  = threadIdx.x;
    const int e0 = blockIdx.x * ET;
    const float4* w4   = (const float4*)(ws + OFF_W);
    const float4* a4   = (const float4*)(ws + OFF_A);
    const float4* wnf4 = (const float4*)(ws + OFF_WNF);
    const float*  nq   = ws + OFF_NQ;
    int eidx[ET];
#pragma unroll
    for (int j = 0; j < ET; ++j) eidx[j] = min(e0 + j, NE - 1);
    float acc[ET];
#pragma unroll
    for (int j = 0; j < ET; ++j) acc[j] = 0.0f;
    for (int dc = 0; dc < D; dc += 4) {
        float4 wv = w4[(dc >> 2)*B + b];
#pragma unroll
        for (int j = 0; j < ET; ++j) {
            float4 ev = *(const float4*)(E + eidx[j]*D + dc);
            acc[j] = fmaf(wv.x, ev.x, acc[j]);
            acc[j] = fmaf(wv.y, ev.y, acc[j]);
            acc[j] = fmaf(wv.z, ev.z, acc[j]);
            acc[j] = fmaf(wv.w, ev.w, acc[j]);
        }
    }
    for (int lc = 0; lc < NL; lc += 4) {
        float4 av = a4[(lc >> 2)*B + b];
        float4 wv = wnf4[(lc >> 2)*B + b];
        float4 q  = *(const float4*)(nq + lc);
#pragma unroll
        for (int j = 0; j < ET; ++j) {
            float4 lv = *(const float4*)(lit + eidx[j]*NL + lc);
            float t0 = av.x - lv.x, t1 = av.y - lv.y, t2 = av.z - lv.z, t3 = av.w - lv.w;
            acc[j] += wv.x * __builtin_amdgcn_exp2f(t0*t0*q.x);
            acc[j] += wv.y * __builtin_amdgcn_exp2f(t1*t1*q.y);
            acc[j] += wv.z * __builtin_amdgcn_exp2f(t2*t2*q.z);
            acc[j] += wv.w * __builtin_amdgcn_exp2f(t3*t3*q.w);
        }
    }
#pragma unroll
    for (int j = 0; j < ET; ++j) {
        float s = 1.0f / (1.0f + __builtin_amdgcn_exp2f(acc[j] * -LOG2E));
        int e = e0 + j;
        if (e < NE) out[b*NE + e] = s;
    }
}

// ---------------- launch ----------------

extern "C" void kernel_launch(void* const* d_in, const int* in_sizes, int n_in,
                              void* d_out, int out_size, void* d_ws, size_t ws_size,
                              hipStream_t stream) {
    const int*   e1_idx = (const int*)d_in[0];
    const int*   r_idx  = (const int*)d_in[1];
    const float* E      = (const float*)d_in[2];
    const float* R      = (const float*)d_in[3];
    const float* nf     = (const float*)d_in[4];
    const float* lit    = (const float*)d_in[5];
    const float* c      = (const float*)d_in[6];
    const float* var    = (const float*)d_in[7];
    float* out = (float*)d_out;
    float* ws  = (float*)d_ws;

    if (ws_size >= WS_NEEDED) {
        prep_all<<<NB_A + NB_B + NB_C, 256, 0, stream>>>(
            e1_idx, r_idx, E, R, nf, lit, c, var, ws);
        score_kernel<<<117 * 16, 256, 0, stream>>>(
            ws + OFF_ET4, ws + OFF_LT4, ws + OFF_ST4,
            ws + OFF_WB, ws + OFF_UB, ws + OFF_FB, out);
    } else {
        prep_kernel_legacy<<<B, 128, 0, stream>>>(e1_idx, r_idx, E, R, nf, lit, c, var, ws);
        main_kernel_legacy<<<(NE + ET - 1)/ET, B, 0, stream>>>(E, lit, ws, out);
    }
}

// Round 12
// 63.898 us; speedup vs baseline: 2.2301x; 2.2301x over previous
//
#include <hip/hip_runtime.h>

#define B     128
#define NE    14951
#define NEP   14976     // 117*128, padded entity count
#define NR    1345
#define D     200
#define NL    116
#define D2    100
#define EB    4
#define LOG2E 1.4426950408889634f

// ---- ws layout (floats), fast path ----
#define OFF_ET8  0                            // [25][NEP] uint4 : E as bf16x8, d-chunked
#define OFF_LT4  (OFF_ET8 + 25*NEP*4)         // [29][NEP] uint2 : lit as bf16x4
#define OFF_WB   (OFF_LT4 + 29*NEP*2)         // [128][200] fp32 : complex weight w[b][d]
#define OFF_UB   (OFF_WB + 128*200)           // [128][116] fp32 : u = -2*q*a
#define OFF_FB   (OFF_UB + 128*116)           // [128][116] fp32 : w' = wnf*exp2(q*a^2)
#define OFF_NQ   (OFF_FB + 128*116)           // [116] fp32      : q = -log2e/var
#define WS_FLOATS (OFF_NQ + 128)
#define WS_NEEDED ((size_t)WS_FLOATS * 4)

__device__ __forceinline__ unsigned bf16rne(float f) {
    unsigned u = __float_as_uint(f);
    u += 0x7FFFu + ((u >> 16) & 1u);
    return u >> 16;
}
#define BF2F_LO(u) __uint_as_float((u) << 16)
#define BF2F_HI(u) __uint_as_float((u) & 0xffff0000u)

// ---------------- fused prep: 3 roles by blockIdx range ----------------
// role A: E -> bf16x8 table   : 234 ebk * 7 cq-groups = 1638 blocks
// role B: lit -> bf16x4 table : 234 ebk * 8 cq-groups = 1872 blocks
// role C: per-batch prep + NQ : 64 blocks
#define NB_A 1638
#define NB_B 1872
#define NB_C 64

__global__ __launch_bounds__(256) void prep_all(
    const int* __restrict__ e1_idx, const int* __restrict__ r_idx,
    const float* __restrict__ E, const float* __restrict__ R,
    const float* __restrict__ nf, const float* __restrict__ lit,
    const float* __restrict__ c, const float* __restrict__ var,
    float* __restrict__ ws)
{
    const int bid = blockIdx.x;
    const int t   = threadIdx.x;

    if (bid < NB_A) {                       // ---- E -> bf16x8 [25][NEP] uint4 ----
        const int ebk = bid % 234;
        const int cq  = (bid / 234) * 4 + (t >> 6);   // 0..27
        const int e   = ebk * 64 + (t & 63);
        if (cq >= 25) return;
        uint4 o = make_uint4(0u, 0u, 0u, 0u);
        if (e < NE) {
            float4 a = *(const float4*)(E + e*D + 8*cq);
            float4 b = *(const float4*)(E + e*D + 8*cq + 4);
            o.x = bf16rne(a.x) | (bf16rne(a.y) << 16);
            o.y = bf16rne(a.z) | (bf16rne(a.w) << 16);
            o.z = bf16rne(b.x) | (bf16rne(b.y) << 16);
            o.w = bf16rne(b.z) | (bf16rne(b.w) << 16);
        }
        ((uint4*)(ws + OFF_ET8))[cq*NEP + e] = o;
    } else if (bid < NB_A + NB_B) {         // ---- lit -> bf16x4 [29][NEP] uint2 ----
        const int idx = bid - NB_A;
        const int ebk = idx % 234;
        const int cq  = (idx / 234) * 4 + (t >> 6);   // 0..31
        const int e   = ebk * 64 + (t & 63);
        if (cq >= 29) return;
        uint2 o = make_uint2(0u, 0u);
        if (e < NE) {
            float4 L = *(const float4*)(lit + e*NL + 4*cq);
            o.x = bf16rne(L.x) | (bf16rne(L.y) << 16);
            o.y = bf16rne(L.z) | (bf16rne(L.w) << 16);
        }
        ((uint2*)(ws + OFF_LT4))[cq*NEP + e] = o;
    } else {                                // ---- per-batch prep + NQ ----
        const int b  = (bid - NB_A - NB_B) * 2 + (t >> 7);
        const int tt = t & 127;
        const int e1 = e1_idx[b];
        const int r  = r_idx[b];
        float* wb = ws + OFF_WB;
        float* ub = ws + OFF_UB;
        float* fb = ws + OFF_FB;
        if (tt < D2) {
            float e1r = E[e1*D + tt],      e1i = E[e1*D + D2 + tt];
            float rr  = R[r*D + tt],       ri  = R[r*D + D2 + tt];
            wb[b*D + tt]      = e1r*rr - e1i*ri;
            wb[b*D + D2 + tt] = e1r*ri + e1i*rr;
        }
        if (tt < NL) {
            float a = lit[e1*NL + tt] - c[tt];
            float q = -LOG2E / var[tt];
            ub[b*NL + tt] = -2.0f * q * a;
            fb[b*NL + tt] = nf[r*NL + tt] * __builtin_amdgcn_exp2f(q * a * a);
            if (b == 0) ws[OFF_NQ + tt] = q;
        }
    }
}

// ---------------- main: lane = entity; bf16 tables; scalar batch operands ----------------

#define SL_STEP(pf, cq) do {                                              \
    float e0f = BF2F_LO((pf).x), e1f = BF2F_HI((pf).x);                   \
    float e2f = BF2F_LO((pf).y), e3f = BF2F_HI((pf).y);                   \
    float e4f = BF2F_LO((pf).z), e5f = BF2F_HI((pf).z);                   \
    float e6f = BF2F_LO((pf).w), e7f = BF2F_HI((pf).w);                   \
    _Pragma("unroll")                                                     \
    for (int j = 0; j < EB; ++j) {                                        \
        float4 wa = *(const float4*)(wb + (b0+j)*D + 8*(cq));             \
        float4 wc = *(const float4*)(wb + (b0+j)*D + 8*(cq) + 4);         \
        acc[j] = fmaf(wa.x, e0f, acc[j]);                                 \
        acc[j] = fmaf(wa.y, e1f, acc[j]);                                 \
        acc[j] = fmaf(wa.z, e2f, acc[j]);                                 \
        acc[j] = fmaf(wa.w, e3f, acc[j]);                                 \
        acc[j] = fmaf(wc.x, e4f, acc[j]);                                 \
        acc[j] = fmaf(wc.y, e5f, acc[j]);                                 \
        acc[j] = fmaf(wc.z, e6f, acc[j]);                                 \
        acc[j] = fmaf(wc.w, e7f, acc[j]);                                 \
    }                                                                     \
} while (0)

#define SN_STEP(lv, cq) do {                                              \
    float L0 = BF2F_LO((lv).x), L1 = BF2F_HI((lv).x);                     \
    float L2 = BF2F_LO((lv).y), L3 = BF2F_HI((lv).y);                     \
    float4 q = *(const float4*)(nq + 4*(cq));                             \
    float s0 = (q.x*L0)*L0, s1 = (q.y*L1)*L1;                             \
    float s2 = (q.z*L2)*L2, s3 = (q.w*L3)*L3;                             \
    _Pragma("unroll")                                                     \
    for (int j = 0; j < EB; ++j) {                                        \
        float4 uj = *(const float4*)(ub + (b0+j)*NL + 4*(cq));            \
        float4 fj = *(const float4*)(fb + (b0+j)*NL + 4*(cq));            \
        acc[j] = fmaf(fj.x, __builtin_amdgcn_exp2f(fmaf(uj.x, L0, s0)), acc[j]); \
        acc[j] = fmaf(fj.y, __builtin_amdgcn_exp2f(fmaf(uj.y, L1, s1)), acc[j]); \
        acc[j] = fmaf(fj.z, __builtin_amdgcn_exp2f(fmaf(uj.z, L2, s2)), acc[j]); \
        acc[j] = fmaf(fj.w, __builtin_amdgcn_exp2f(fmaf(uj.w, L3, s3)), acc[j]); \
    }                                                                     \
} while (0)

__global__ __launch_bounds__(128) void score_kernel(
    const float* __restrict__ et8, const float* __restrict__ lt4,
    const float* __restrict__ wb,  const float* __restrict__ ub,
    const float* __restrict__ fb,  const float* __restrict__ nq,
    float* __restrict__ out)
{
    // grid = 3744 = 117 eblk * 32 bblk; partition e-range per XCD (lid&7)
    const int lid  = blockIdx.x;
    const int p    = (lid & 7) * 468 + (lid >> 3);
    const int eblk = p >> 5;            // 0..116
    const int bblk = p & 31;            // 0..31
    const int e    = eblk * 128 + threadIdx.x;
    const int b0   = bblk * EB;

    float acc[EB];
#pragma unroll
    for (int j = 0; j < EB; ++j) acc[j] = 0.f;

    const uint4* E4 = (const uint4*)et8;
    const uint2* L4 = (const uint2*)lt4;

    // ---- score_l: 25 bf16x8 chunks, 4-deep rolling prefetch, no clamps ----
    {
        uint4 pf0 = E4[0*NEP + e];
        uint4 pf1 = E4[1*NEP + e];
        uint4 pf2 = E4[2*NEP + e];
        uint4 pf3 = E4[3*NEP + e];
        for (int cq0 = 0; cq0 < 20; cq0 += 4) {
            SL_STEP(pf0, cq0 + 0); pf0 = E4[(cq0 + 4)*NEP + e];
            SL_STEP(pf1, cq0 + 1); pf1 = E4[(cq0 + 5)*NEP + e];
            SL_STEP(pf2, cq0 + 2); pf2 = E4[(cq0 + 6)*NEP + e];
            SL_STEP(pf3, cq0 + 3); pf3 = E4[(cq0 + 7)*NEP + e];
        }
        // slots now hold chunks 20..23
        SL_STEP(pf0, 20); pf0 = E4[24*NEP + e];
        SL_STEP(pf1, 21);
        SL_STEP(pf2, 22);
        SL_STEP(pf3, 23);
        SL_STEP(pf0, 24);
    }

    // ---- score_n: 29 bf16x4 chunks, 4-deep rolling prefetch, no clamps ----
    {
        uint2 lv0 = L4[0*NEP + e];
        uint2 lv1 = L4[1*NEP + e];
        uint2 lv2 = L4[2*NEP + e];
        uint2 lv3 = L4[3*NEP + e];
        for (int cq0 = 0; cq0 < 24; cq0 += 4) {
            SN_STEP(lv0, cq0 + 0); lv0 = L4[(cq0 + 4)*NEP + e];
            SN_STEP(lv1, cq0 + 1); lv1 = L4[(cq0 + 5)*NEP + e];
            SN_STEP(lv2, cq0 + 2); lv2 = L4[(cq0 + 6)*NEP + e];
            SN_STEP(lv3, cq0 + 3); lv3 = L4[(cq0 + 7)*NEP + e];
        }
        // slots now hold chunks 24..27
        SN_STEP(lv0, 24); lv0 = L4[28*NEP + e];
        SN_STEP(lv1, 25);
        SN_STEP(lv2, 26);
        SN_STEP(lv3, 27);
        SN_STEP(lv0, 28);
    }

    // ---- sigmoid + coalesced store ----
    if (e < NE) {
#pragma unroll
        for (int j = 0; j < EB; ++j) {
            float s = __builtin_amdgcn_rcpf(1.0f + __builtin_amdgcn_exp2f(acc[j] * -LOG2E));
            out[(b0+j)*NE + e] = s;
        }
    }
}

// ---------------- legacy fallback (ws < 10 MB) ----------------

#define ET  4
#define OFF_W   0
#define OFF_A   25600
#define OFF_WNF 40448
#define OFF_NQL 55296

__global__ __launch_bounds__(128) void prep_kernel_legacy(
    const int* __restrict__ e1_idx, const int* __restrict__ r_idx,
    const float* __restrict__ E, const float* __restrict__ R,
    const float* __restrict__ nf, const float* __restrict__ lit,
    const float* __restrict__ c, const float* __restrict__ var,
    float* __restrict__ ws)
{
    const int b = blockIdx.x;
    const int t = threadIdx.x;
    const int e1 = e1_idx[b];
    const int r  = r_idx[b];
    if (t < D2) {
        float e1r = E[e1*D + t], e1i = E[e1*D + D2 + t];
        float rr  = R[r*D + t],  ri  = R[r*D + D2 + t];
        ws[OFF_W + (t >> 2)*512        + (b << 2) + (t & 3)] = e1r*rr - e1i*ri;
        ws[OFF_W + ((t >> 2) + 25)*512 + (b << 2) + (t & 3)] = e1r*ri + e1i*rr;
    }
    if (t < NL) {
        ws[OFF_A   + (t >> 2)*512 + (b << 2) + (t & 3)] = lit[e1*NL + t] - c[t];
        ws[OFF_WNF + (t >> 2)*512 + (b << 2) + (t & 3)] = nf[r*NL + t];
        if (b == 0) ws[OFF_NQL + t] = -LOG2E / var[t];
    }
}

__global__ __launch_bounds__(128) void main_kernel_legacy(
    const float* __restrict__ E, const float* __restrict__ lit,
    const float* __restrict__ ws, float* __restrict__ out)
{
    const int b  = threadIdx.x;
    const int e0 = blockIdx.x * ET;
    const float4* w4   = (const float4*)(ws + OFF_W);
    const float4* a4   = (const float4*)(ws + OFF_A);
    const float4* wnf4 = (const float4*)(ws + OFF_WNF);
    const float*  nqv  = ws + OFF_NQL;
    int eidx[ET];
#pragma unroll
    for (int j = 0; j < ET; ++j) eidx[j] = min(e0 + j, NE - 1);
    float acc[ET];
#pragma unroll
    for (int j = 0; j < ET; ++j) acc[j] = 0.0f;
    for (int dc = 0; dc < D; dc += 4) {
        float4 wv = w4[(dc >> 2)*B + b];
#pragma unroll
        for (int j = 0; j < ET; ++j) {
            float4 ev = *(const float4*)(E + eidx[j]*D + dc);
            acc[j] = fmaf(wv.x, ev.x, acc[j]);
            acc[j] = fmaf(wv.y, ev.y, acc[j]);
            acc[j] = fmaf(wv.z, ev.z, acc[j]);
            acc[j] = fmaf(wv.w, ev.w, acc[j]);
        }
    }
    for (int lc = 0; lc < NL; lc += 4) {
        float4 av = a4[(lc >> 2)*B + b];
        float4 wv = wnf4[(lc >> 2)*B + b];
        float4 q  = *(const float4*)(nqv + lc);
#pragma unroll
        for (int j = 0; j < ET; ++j) {
            float4 lv = *(const float4*)(lit + eidx[j]*NL + lc);
            float t0 = av.x - lv.x, t1 = av.y - lv.y, t2 = av.z - lv.z, t3 = av.w - lv.w;
            acc[j] += wv.x * __builtin_amdgcn_exp2f(t0*t0*q.x);
            acc[j] += wv.y * __builtin_amdgcn_exp2f(t1*t1*q.y);
            acc[j] += wv.z * __builtin_amdgcn_exp2f(t2*t2*q.z);
            acc[j] += wv.w * __builtin_amdgcn_exp2f(t3*t3*q.w);
        }
    }
#pragma unroll
    for (int j = 0; j < ET; ++j) {
        float s = 1.0f / (1.0f + __builtin_amdgcn_exp2f(acc[j] * -LOG2E));
        int e = e0 + j;
        if (e < NE) out[b*NE + e] = s;
    }
}

// ---------------- launch ----------------

extern "C" void kernel_launch(void* const* d_in, const int* in_sizes, int n_in,
                              void* d_out, int out_size, void* d_ws, size_t ws_size,
                              hipStream_t stream) {
    const int*   e1_idx = (const int*)d_in[0];
    const int*   r_idx  = (const int*)d_in[1];
    const float* E      = (const float*)d_in[2];
    const float* R      = (const float*)d_in[3];
    const float* nf     = (const float*)d_in[4];
    const float* lit    = (const float*)d_in[5];
    const float* c      = (const float*)d_in[6];
    const float* var    = (const float*)d_in[7];
    float* out = (float*)d_out;
    float* ws  = (float*)d_ws;

    if (ws_size >= WS_NEEDED) {
        prep_all<<<NB_A + NB_B + NB_C, 256, 0, stream>>>(
            e1_idx, r_idx, E, R, nf, lit, c, var, ws);
        score_kernel<<<117 * 32, 128, 0, stream>>>(
            ws + OFF_ET8, ws + OFF_LT4,
            ws + OFF_WB, ws + OFF_UB, ws + OFF_FB, ws + OFF_NQ, out);
    } else {
        prep_kernel_legacy<<<B, 128, 0, stream>>>(e1_idx, r_idx, E, R, nf, lit, c, var, ws);
        main_kernel_legacy<<<(NE + ET - 1)/ET, B, 0, stream>>>(E, lit, ws, out);
    }
}

// Round 13
// 53.528 us; speedup vs baseline: 2.6622x; 1.1937x over previous
//
#include <hip/hip_runtime.h>

#define B     128
#define NE    14951
#define NEP   14976     // 117*128 = 936*16, padded entity count
#define NR    1345
#define D     200
#define NL    116
#define D2    100
#define EB    4
#define LOG2E 1.4426950408889634f

typedef __attribute__((ext_vector_type(8))) short bf16x8;
typedef __attribute__((ext_vector_type(4))) float f32x4;

// ---- ws layout (floats), fast path ----
#define OFF_ET   0                            // uint4[28][NEP] : E bf16x8, slot s = d 8s..8s+7 (d>=200 zero)
#define OFF_WA   (OFF_ET + 28*NEP*4)          // uint4[28][128] : w  bf16x8, same k-chunking
#define OFF_LT   (OFF_WA + 28*128*4)          // uint2[29][NEP] : lit bf16x4
#define OFF_SL   (OFF_LT + 29*NEP*2)          // float[128][NEP]: score_l
#define OFF_UB   (OFF_SL + 128*NEP)           // [128][116] fp32: u = -2*q*a
#define OFF_FB   (OFF_UB + 128*116)           // [128][116] fp32: w' = wnf*exp2(q*a^2)
#define OFF_NQ   (OFF_FB + 128*116)           // [116] fp32     : q
#define WS_FLOATS (OFF_NQ + 128)
#define WS_NEEDED ((size_t)WS_FLOATS * 4)

__device__ __forceinline__ unsigned bf16rne(float f) {
    unsigned u = __float_as_uint(f);
    u += 0x7FFFu + ((u >> 16) & 1u);
    return u >> 16;
}
#define BF2F_LO(u) __uint_as_float((u) << 16)
#define BF2F_HI(u) __uint_as_float((u) & 0xffff0000u)

// ---------------- fused prep: 3 roles by blockIdx range ----------------
// role A: E -> ET bf16x8 [28][NEP] : 234 * 7 = 1638 blocks
// role B: lit -> LT bf16x4 [29][NEP]: 234 * 8 = 1872 blocks
// role C: per-batch prep + WA pack : 64 blocks (2 b each)
#define NB_A 1638
#define NB_B 1872
#define NB_C 64

__global__ __launch_bounds__(256) void prep_all(
    const int* __restrict__ e1_idx, const int* __restrict__ r_idx,
    const float* __restrict__ E, const float* __restrict__ R,
    const float* __restrict__ nf, const float* __restrict__ lit,
    const float* __restrict__ c, const float* __restrict__ var,
    float* __restrict__ ws)
{
    __shared__ float lwb[2][224];
    const int bid = blockIdx.x;
    const int t   = threadIdx.x;

    if (bid < NB_A) {                       // ---- E -> bf16x8 [28][NEP] ----
        const int ebk = bid % 234;
        const int cq  = (bid / 234) * 4 + (t >> 6);   // 0..27
        const int e   = ebk * 64 + (t & 63);
        uint4 o = make_uint4(0u, 0u, 0u, 0u);
        if (e < NE && cq < 25) {            // d = 8cq..8cq+7 < 200
            float4 a = *(const float4*)(E + e*D + 8*cq);
            float4 b = *(const float4*)(E + e*D + 8*cq + 4);
            o.x = bf16rne(a.x) | (bf16rne(a.y) << 16);
            o.y = bf16rne(a.z) | (bf16rne(a.w) << 16);
            o.z = bf16rne(b.x) | (bf16rne(b.y) << 16);
            o.w = bf16rne(b.z) | (bf16rne(b.w) << 16);
        }
        ((uint4*)(ws + OFF_ET))[cq*NEP + e] = o;
    } else if (bid < NB_A + NB_B) {         // ---- lit -> bf16x4 [29][NEP] ----
        const int idx = bid - NB_A;
        const int ebk = idx % 234;
        const int cq  = (idx / 234) * 4 + (t >> 6);   // 0..31
        const int e   = ebk * 64 + (t & 63);
        if (cq >= 29) return;
        uint2 o = make_uint2(0u, 0u);
        if (e < NE) {
            float4 L = *(const float4*)(lit + e*NL + 4*cq);
            o.x = bf16rne(L.x) | (bf16rne(L.y) << 16);
            o.y = bf16rne(L.z) | (bf16rne(L.w) << 16);
        }
        ((uint2*)(ws + OFF_LT))[cq*NEP + e] = o;
    } else {                                // ---- per-batch prep + WA pack ----
        const int cb  = bid - NB_A - NB_B;  // 0..63
        const int sub = t >> 7;             // 0..1
        const int b   = cb*2 + sub;
        const int tt  = t & 127;
        const int e1 = e1_idx[b];
        const int r  = r_idx[b];
        if (tt < D2) {
            float e1r = E[e1*D + tt],      e1i = E[e1*D + D2 + tt];
            float rr  = R[r*D + tt],       ri  = R[r*D + D2 + tt];
            lwb[sub][tt]      = e1r*rr - e1i*ri;
            lwb[sub][D2 + tt] = e1r*ri + e1i*rr;
        }
        if (tt >= 100 && tt < 124) lwb[sub][100 + tt] = 0.f;   // d = 200..223
        if (tt < NL) {
            float a = lit[e1*NL + tt] - c[tt];
            float q = -LOG2E / var[tt];
            (ws + OFF_UB)[b*NL + tt] = -2.0f * q * a;
            (ws + OFF_FB)[b*NL + tt] = nf[r*NL + tt] * __builtin_amdgcn_exp2f(q * a * a);
            if (b == 0) (ws + OFF_NQ)[tt] = q;
        }
        __syncthreads();
        if (tt < 28) {
            const float* w8 = &lwb[sub][8*tt];
            uint4 o;
            o.x = bf16rne(w8[0]) | (bf16rne(w8[1]) << 16);
            o.y = bf16rne(w8[2]) | (bf16rne(w8[3]) << 16);
            o.z = bf16rne(w8[4]) | (bf16rne(w8[5]) << 16);
            o.w = bf16rne(w8[6]) | (bf16rne(w8[7]) << 16);
            ((uint4*)(ws + OFF_WA))[tt*128 + b] = o;
        }
    }
}

// ---------------- gemm: SL[b][e] = sum_d w[b][d]*E[e][d], bf16 MFMA ----------------
// 16x16 tiles: m-dim = b, n-dim = e. K = 224 (7 x mfma_f32_16x16x32_bf16).
// A lane l: m = l&15, k-chunk = slot kc*4 + (l>>4). B lane l: n = l&15, same k-chunk.
// C (m89-verified): col = lane&15 (e), row = (lane>>4)*4 + reg (b).

__global__ __launch_bounds__(256) void gemm_kernel(
    const uint4* __restrict__ et, const uint4* __restrict__ wa,
    float* __restrict__ sl)
{
    const int gw = blockIdx.x * 4 + (threadIdx.x >> 6);  // 0..7487
    const int l  = threadIdx.x & 63;
    const int mb = gw / 936;            // 0..7   (b-tile)
    const int nb = gw - mb*936;         // 0..935 (e-tile)
    const int lane16 = l & 15;
    const int grp    = l >> 4;
    const int e = nb*16 + lane16;

    f32x4 acc = {0.f, 0.f, 0.f, 0.f};
#pragma unroll
    for (int kc = 0; kc < 7; ++kc) {
        const int s = kc*4 + grp;
        bf16x8 a = *(const bf16x8*)(wa + s*128 + mb*16 + lane16);
        bf16x8 b = *(const bf16x8*)(et + s*NEP + e);
        acc = __builtin_amdgcn_mfma_f32_16x16x32_bf16(a, b, acc, 0, 0, 0);
    }
    const int brow = mb*16 + grp*4;
#pragma unroll
    for (int r = 0; r < 4; ++r)
        sl[(brow + r)*NEP + e] = acc[r];
}

// ---------------- score_n: lane = entity; scalar batch operands ----------------

#define SN_STEP(lv, cq) do {                                              \
    float L0 = BF2F_LO((lv).x), L1 = BF2F_HI((lv).x);                     \
    float L2 = BF2F_LO((lv).y), L3 = BF2F_HI((lv).y);                     \
    float4 q = *(const float4*)(nq + 4*(cq));                             \
    float s0 = (q.x*L0)*L0, s1 = (q.y*L1)*L1;                             \
    float s2 = (q.z*L2)*L2, s3 = (q.w*L3)*L3;                             \
    _Pragma("unroll")                                                     \
    for (int j = 0; j < EB; ++j) {                                        \
        float4 uj = *(const float4*)(ub + (b0+j)*NL + 4*(cq));            \
        float4 fj = *(const float4*)(fb + (b0+j)*NL + 4*(cq));            \
        acc[j] = fmaf(fj.x, __builtin_amdgcn_exp2f(fmaf(uj.x, L0, s0)), acc[j]); \
        acc[j] = fmaf(fj.y, __builtin_amdgcn_exp2f(fmaf(uj.y, L1, s1)), acc[j]); \
        acc[j] = fmaf(fj.z, __builtin_amdgcn_exp2f(fmaf(uj.z, L2, s2)), acc[j]); \
        acc[j] = fmaf(fj.w, __builtin_amdgcn_exp2f(fmaf(uj.w, L3, s3)), acc[j]); \
    }                                                                     \
} while (0)

__global__ __launch_bounds__(128) void score_kernel(
    const float* __restrict__ lt4, const float* __restrict__ sl,
    const float* __restrict__ ub,  const float* __restrict__ fb,
    const float* __restrict__ nq,  float* __restrict__ out)
{
    // grid = 3744 = 117 eblk * 32 bblk; partition e-range per XCD (lid&7)
    const int lid  = blockIdx.x;
    const int p    = (lid & 7) * 468 + (lid >> 3);
    const int eblk = p >> 5;            // 0..116
    const int bblk = p & 31;            // 0..31
    const int e    = eblk * 128 + threadIdx.x;
    const int b0   = bblk * EB;

    // ---- acc init from MFMA score_l ----
    float acc[EB];
#pragma unroll
    for (int j = 0; j < EB; ++j) acc[j] = sl[(b0+j)*NEP + e];

    const uint2* L4 = (const uint2*)lt4;

    // ---- score_n: 29 bf16x4 chunks, 4-deep rolling prefetch, no clamps ----
    {
        uint2 lv0 = L4[0*NEP + e];
        uint2 lv1 = L4[1*NEP + e];
        uint2 lv2 = L4[2*NEP + e];
        uint2 lv3 = L4[3*NEP + e];
        for (int cq0 = 0; cq0 < 24; cq0 += 4) {
            SN_STEP(lv0, cq0 + 0); lv0 = L4[(cq0 + 4)*NEP + e];
            SN_STEP(lv1, cq0 + 1); lv1 = L4[(cq0 + 5)*NEP + e];
            SN_STEP(lv2, cq0 + 2); lv2 = L4[(cq0 + 6)*NEP + e];
            SN_STEP(lv3, cq0 + 3); lv3 = L4[(cq0 + 7)*NEP + e];
        }
        SN_STEP(lv0, 24); lv0 = L4[28*NEP + e];
        SN_STEP(lv1, 25);
        SN_STEP(lv2, 26);
        SN_STEP(lv3, 27);
        SN_STEP(lv0, 28);
    }

    // ---- sigmoid + coalesced store ----
    if (e < NE) {
#pragma unroll
        for (int j = 0; j < EB; ++j) {
            float s = __builtin_amdgcn_rcpf(1.0f + __builtin_amdgcn_exp2f(acc[j] * -LOG2E));
            out[(b0+j)*NE + e] = s;
        }
    }
}

// ---------------- legacy fallback (ws too small) ----------------

#define ET  4
#define OFF_W   0
#define OFF_A   25600
#define OFF_WNF 40448
#define OFF_NQL 55296

__global__ __launch_bounds__(128) void prep_kernel_legacy(
    const int* __restrict__ e1_idx, const int* __restrict__ r_idx,
    const float* __restrict__ E, const float* __restrict__ R,
    const float* __restrict__ nf, const float* __restrict__ lit,
    const float* __restrict__ c, const float* __restrict__ var,
    float* __restrict__ ws)
{
    const int b = blockIdx.x;
    const int t = threadIdx.x;
    const int e1 = e1_idx[b];
    const int r  = r_idx[b];
    if (t < D2) {
        float e1r = E[e1*D + t], e1i = E[e1*D + D2 + t];
        float rr  = R[r*D + t],  ri  = R[r*D + D2 + t];
        ws[OFF_W + (t >> 2)*512        + (b << 2) + (t & 3)] = e1r*rr - e1i*ri;
        ws[OFF_W + ((t >> 2) + 25)*512 + (b << 2) + (t & 3)] = e1r*ri + e1i*rr;
    }
    if (t < NL) {
        ws[OFF_A   + (t >> 2)*512 + (b << 2) + (t & 3)] = lit[e1*NL + t] - c[t];
        ws[OFF_WNF + (t >> 2)*512 + (b << 2) + (t & 3)] = nf[r*NL + t];
        if (b == 0) ws[OFF_NQL + t] = -LOG2E / var[t];
    }
}

__global__ __launch_bounds__(128) void main_kernel_legacy(
    const float* __restrict__ E, const float* __restrict__ lit,
    const float* __restrict__ ws, float* __restrict__ out)
{
    const int b  = threadIdx.x;
    const int e0 = blockIdx.x * ET;
    const float4* w4   = (const float4*)(ws + OFF_W);
    const float4* a4   = (const float4*)(ws + OFF_A);
    const float4* wnf4 = (const float4*)(ws + OFF_WNF);
    const float*  nqv  = ws + OFF_NQL;
    int eidx[ET];
#pragma unroll
    for (int j = 0; j < ET; ++j) eidx[j] = min(e0 + j, NE - 1);
    float acc[ET];
#pragma unroll
    for (int j = 0; j < ET; ++j) acc[j] = 0.0f;
    for (int dc = 0; dc < D; dc += 4) {
        float4 wv = w4[(dc >> 2)*B + b];
#pragma unroll
        for (int j = 0; j < ET; ++j) {
            float4 ev = *(const float4*)(E + eidx[j]*D + dc);
            acc[j] = fmaf(wv.x, ev.x, acc[j]);
            acc[j] = fmaf(wv.y, ev.y, acc[j]);
            acc[j] = fmaf(wv.z, ev.z, acc[j]);
            acc[j] = fmaf(wv.w, ev.w, acc[j]);
        }
    }
    for (int lc = 0; lc < NL; lc += 4) {
        float4 av = a4[(lc >> 2)*B + b];
        float4 wv = wnf4[(lc >> 2)*B + b];
        float4 q  = *(const float4*)(nqv + lc);
#pragma unroll
        for (int j = 0; j < ET; ++j) {
            float4 lv = *(const float4*)(lit + eidx[j]*NL + lc);
            float t0 = av.x - lv.x, t1 = av.y - lv.y, t2 = av.z - lv.z, t3 = av.w - lv.w;
            acc[j] += wv.x * __builtin_amdgcn_exp2f(t0*t0*q.x);
            acc[j] += wv.y * __builtin_amdgcn_exp2f(t1*t1*q.y);
            acc[j] += wv.z * __builtin_amdgcn_exp2f(t2*t2*q.z);
            acc[j] += wv.w * __builtin_amdgcn_exp2f(t3*t3*q.w);
        }
    }
#pragma unroll
    for (int j = 0; j < ET; ++j) {
        float s = 1.0f / (1.0f + __builtin_amdgcn_exp2f(acc[j] * -LOG2E));
        int e = e0 + j;
        if (e < NE) out[b*NE + e] = s;
    }
}

// ---------------- launch ----------------

extern "C" void kernel_launch(void* const* d_in, const int* in_sizes, int n_in,
                              void* d_out, int out_size, void* d_ws, size_t ws_size,
                              hipStream_t stream) {
    const int*   e1_idx = (const int*)d_in[0];
    const int*   r_idx  = (const int*)d_in[1];
    const float* E      = (const float*)d_in[2];
    const float* R      = (const float*)d_in[3];
    const float* nf     = (const float*)d_in[4];
    const float* lit    = (const float*)d_in[5];
    const float* c      = (const float*)d_in[6];
    const float* var    = (const float*)d_in[7];
    float* out = (float*)d_out;
    float* ws  = (float*)d_ws;

    if (ws_size >= WS_NEEDED) {
        prep_all<<<NB_A + NB_B + NB_C, 256, 0, stream>>>(
            e1_idx, r_idx, E, R, nf, lit, c, var, ws);
        gemm_kernel<<<1872, 256, 0, stream>>>(
            (const uint4*)(ws + OFF_ET), (const uint4*)(ws + OFF_WA), ws + OFF_SL);
        score_kernel<<<117 * 32, 128, 0, stream>>>(
            ws + OFF_LT, ws + OFF_SL, ws + OFF_UB, ws + OFF_FB, ws + OFF_NQ, out);
    } else {
        prep_kernel_legacy<<<B, 128, 0, stream>>>(e1_idx, r_idx, E, R, nf, lit, c, var, ws);
        main_kernel_legacy<<<(NE + ET - 1)/ET, B, 0, stream>>>(E, lit, ws, out);
    }
}